// Round 1
// baseline (937.803 us; speedup 1.0000x reference)
//
#include <hip/hip_runtime.h>

// Problem constants
#define S 4096
#define C 2048
#define H 16
#define D 128
#define EPS 1.1920929e-07f
#define SCALE 0.08838834764831845f  // 1/sqrt(128)

typedef __attribute__((ext_vector_type(8))) short short8;   // 8 bf16 = 4 VGPRs (MFMA A/B frag)
typedef __attribute__((ext_vector_type(4))) float f32x4;    // MFMA C/D frag

__device__ __forceinline__ unsigned short f2bf(float f) {
  unsigned int u = __builtin_bit_cast(unsigned int, f);
  u += 0x7fff + ((u >> 16) & 1);  // round-to-nearest-even
  return (unsigned short)(u >> 16);
}
__device__ __forceinline__ float bf2f(unsigned short v) {
  unsigned int u = ((unsigned int)v) << 16;
  return __builtin_bit_cast(float, u);
}

// ---------------- fp32 -> bf16 convert ----------------
__global__ void cvt_kernel(const float* __restrict__ src,
                           unsigned short* __restrict__ dst, int n) {
  int i = (blockIdx.x * 256 + threadIdx.x) * 4;
  if (i >= n) return;
  float4 v = *(const float4*)(src + i);
  ushort4 o;
  o.x = f2bf(v.x); o.y = f2bf(v.y); o.z = f2bf(v.z); o.w = f2bf(v.w);
  *(ushort4*)(dst + i) = o;
}

// ---------------- bf16 GEMM: out[m][n] = sum_k A[m][k]*B[n][k] + bias[n] ----------------
// M=S, N=C, K=C fixed. mode 0: fp32 out [M][N]. mode 1: bf16 out in head layout [H][S][D].
__global__ __launch_bounds__(256) void gemm_bt(const unsigned short* __restrict__ A,
                                               const unsigned short* __restrict__ B,
                                               const float* __restrict__ bias,
                                               void* __restrict__ out, int mode) {
  __shared__ __align__(16) unsigned short Al[128 * 72];  // 128 rows x 64 + 8 pad
  __shared__ __align__(16) unsigned short Bl[128 * 72];
  const int t = threadIdx.x;
  const int w = t >> 6, lane = t & 63;
  const int lq = lane & 15, quad = lane >> 4;
  const int wm = w & 1, wn = w >> 1;
  const int m0 = blockIdx.y * 128, n0 = blockIdx.x * 128;
  f32x4 acc[4][4] = {};
  float biasv[4];
  for (int nt = 0; nt < 4; nt++) biasv[nt] = bias[n0 + wn * 64 + nt * 16 + lq];
  const int srow = t >> 3;        // 0..31
  const int scol = (t & 7) * 8;   // 0..56
  for (int k0 = 0; k0 < C; k0 += 64) {
    __syncthreads();
    for (int p = 0; p < 4; p++) {
      int row = p * 32 + srow;
      *(uint4*)&Al[row * 72 + scol] = *(const uint4*)(A + (size_t)(m0 + row) * C + k0 + scol);
      *(uint4*)&Bl[row * 72 + scol] = *(const uint4*)(B + (size_t)(n0 + row) * C + k0 + scol);
    }
    __syncthreads();
    for (int ks = 0; ks < 2; ks++) {
      short8 af[4], bf[4];
      for (int mt = 0; mt < 4; mt++)
        af[mt] = *(const short8*)&Al[(wm * 64 + mt * 16 + lq) * 72 + ks * 32 + quad * 8];
      for (int nt = 0; nt < 4; nt++)
        bf[nt] = *(const short8*)&Bl[(wn * 64 + nt * 16 + lq) * 72 + ks * 32 + quad * 8];
      for (int mt = 0; mt < 4; mt++)
        for (int nt = 0; nt < 4; nt++)
          acc[mt][nt] = __builtin_amdgcn_mfma_f32_16x16x32_bf16(af[mt], bf[nt], acc[mt][nt], 0, 0, 0);
    }
  }
  for (int mt = 0; mt < 4; mt++) {
    for (int nt = 0; nt < 4; nt++) {
      int n = n0 + wn * 64 + nt * 16 + lq;
      for (int r = 0; r < 4; r++) {
        int m = m0 + wm * 64 + mt * 16 + quad * 4 + r;  // C/D: col=lane&15, row=quad*4+reg
        float v = acc[mt][nt][r] + biasv[nt];
        if (mode == 0) {
          ((float*)out)[(size_t)m * C + n] = v;
        } else {
          // head layout: [h=n>>7][m][d=n&127]
          ((unsigned short*)out)[(size_t)(n >> 7) * S * D + (size_t)m * D + (n & 127)] = f2bf(v);
        }
      }
    }
  }
}

// ---------------- fused RMSNorm (over D) + rotary, in place on [H][S][D] bf16 ----------------
__global__ __launch_bounds__(256) void rmsrope_kernel(unsigned short* __restrict__ io,
                                                      const float* __restrict__ wgt,
                                                      const float* __restrict__ rope,
                                                      float scale) {
  int wid = (blockIdx.x * 256 + threadIdx.x) >> 6;  // wave id = h*S + s
  int lane = threadIdx.x & 63;
  int s = wid & (S - 1);
  unsigned short* row = io + (size_t)wid * D;
  unsigned int pr = *(unsigned int*)(row + lane * 2);
  float a = bf2f((unsigned short)(pr & 0xffff));
  float b = bf2f((unsigned short)(pr >> 16));
  float ss = a * a + b * b;
  for (int m = 1; m < 64; m <<= 1) ss += __shfl_xor(ss, m);
  float inv = rsqrtf(ss * (1.0f / 128.0f) + EPS);
  float2 wv = *(const float2*)(wgt + lane * 2);
  float an = a * inv * wv.x, bn = b * inv * wv.y;
  float4 r = *(const float4*)(rope + (size_t)s * 256 + lane * 4);  // [p][j][k]
  float o0 = (r.x * an + r.y * bn) * scale;
  float o1 = (r.z * an + r.w * bn) * scale;
  *(unsigned int*)(row + lane * 2) = (unsigned int)f2bf(o0) | ((unsigned int)f2bf(o1) << 16);
}

// ---------------- V transpose: [H][S][D] bf16 -> [H][D][S] bf16 ----------------
__global__ __launch_bounds__(256) void transpose_v(const unsigned short* __restrict__ vh,
                                                   unsigned short* __restrict__ vt) {
  __shared__ unsigned short tile[64][72];
  int h = blockIdx.z, s0 = blockIdx.x * 64, d0 = blockIdx.y * 64;
  int t = threadIdx.x;
  for (int p = 0; p < 2; p++) {
    int sl = p * 32 + (t >> 3);
    int d8 = (t & 7) * 8;
    *(uint4*)&tile[sl][d8] = *(const uint4*)(vh + ((size_t)h * S + s0 + sl) * D + d0 + d8);
  }
  __syncthreads();
  for (int p = 0; p < 2; p++) {
    int dl = p * 32 + (t >> 3);
    int s8 = (t & 7) * 8;
    unsigned short vals[8];
    for (int i = 0; i < 8; i++) vals[i] = tile[s8 + i][dl];
    *(uint4*)(vt + ((size_t)h * D + d0 + dl) * S + s0 + s8) = *(uint4*)vals;
  }
}

// ---------------- flash attention: Q,K [H][S][D], V^T [H][D][S] -> ao [S][C] bf16 ----------------
// Block: 4 waves, each wave owns 16 q rows (softmax wave-local). KV tiles of 64.
__global__ __launch_bounds__(256) void flash_kernel(const unsigned short* __restrict__ qh,
                                                    const unsigned short* __restrict__ kh,
                                                    const unsigned short* __restrict__ vt,
                                                    unsigned short* __restrict__ ao) {
  __shared__ __align__(16) unsigned short Klds[64 * 136];   // [j][d], pad +8
  __shared__ __align__(16) unsigned short Vlds[128 * 72];   // [d][j], pad +8
  __shared__ __align__(16) unsigned short Plds[4 * 16 * 72];// per-wave [16][64+8]
  const int h = blockIdx.y;
  const int i0 = blockIdx.x * 64;
  const int t = threadIdx.x;
  const int w = t >> 6, lane = t & 63;
  const int lq = lane & 15, quad = lane >> 4;

  // Q fragments in registers (A layout: m=lane&15, k=quad*8+j), scale pre-folded in rmsrope
  const unsigned short* Qbase = qh + ((size_t)h * S + i0 + w * 16 + lq) * D;
  short8 qfrag[4];
  for (int kt = 0; kt < 4; kt++)
    qfrag[kt] = *(const short8*)(Qbase + kt * 32 + quad * 8);

  f32x4 oacc[8] = {};
  float mrun[4], lrun[4];
  for (int r = 0; r < 4; r++) { mrun[r] = -1e30f; lrun[r] = 0.0f; }

  const unsigned short* Kbase = kh + (size_t)h * S * D;
  const unsigned short* Vbase = vt + (size_t)h * D * S;
  unsigned short* Pw = Plds + w * 16 * 72;

  for (int j0 = 0; j0 < S; j0 += 64) {
    __syncthreads();
    // stage K tile [64][128]
    for (int p = 0; p < 4; p++) {
      int j = p * 16 + (t >> 4);
      int d8 = (t & 15) * 8;
      *(uint4*)&Klds[j * 136 + d8] = *(const uint4*)(Kbase + (size_t)(j0 + j) * D + d8);
    }
    // stage V^T tile [128][64]
    for (int p = 0; p < 4; p++) {
      int d = p * 32 + (t >> 3);
      int c8 = (t & 7) * 8;
      *(uint4*)&Vlds[d * 72 + c8] = *(const uint4*)(Vbase + (size_t)d * S + j0 + c8);
    }
    __syncthreads();

    // S = Q K^T (scaled)
    f32x4 sacc[4] = {};
    for (int kt = 0; kt < 4; kt++) {
      for (int nt = 0; nt < 4; nt++) {
        short8 bf = *(const short8*)&Klds[(nt * 16 + lq) * 136 + kt * 32 + quad * 8];
        sacc[nt] = __builtin_amdgcn_mfma_f32_16x16x32_bf16(qfrag[kt], bf, sacc[nt], 0, 0, 0);
      }
    }
    // online softmax (per reg = per q-row, replicated across the 16-lane group)
    float mnew[4], alpha[4], rsum[4];
    for (int r = 0; r < 4; r++) {
      float v = fmaxf(fmaxf(sacc[0][r], sacc[1][r]), fmaxf(sacc[2][r], sacc[3][r]));
      v = fmaxf(v, __shfl_xor(v, 1));
      v = fmaxf(v, __shfl_xor(v, 2));
      v = fmaxf(v, __shfl_xor(v, 4));
      v = fmaxf(v, __shfl_xor(v, 8));
      mnew[r] = fmaxf(mrun[r], v);
      alpha[r] = __expf(mrun[r] - mnew[r]);
      mrun[r] = mnew[r];
      rsum[r] = 0.0f;
    }
    for (int nt = 0; nt < 4; nt++) {
      for (int r = 0; r < 4; r++) {
        float p = __expf(sacc[nt][r] - mnew[r]);
        rsum[r] += p;
        Pw[(quad * 4 + r) * 72 + nt * 16 + lq] = f2bf(p);  // C-layout -> LDS
      }
    }
    for (int r = 0; r < 4; r++) {
      float v = rsum[r];
      v += __shfl_xor(v, 1);
      v += __shfl_xor(v, 2);
      v += __shfl_xor(v, 4);
      v += __shfl_xor(v, 8);
      lrun[r] = lrun[r] * alpha[r] + v;
    }
    for (int i = 0; i < 8; i++)
      for (int r = 0; r < 4; r++) oacc[i][r] *= alpha[r];
    // O += P V  (A-frag from per-wave P region, B-frag from V^T)
    for (int kt = 0; kt < 2; kt++) {
      short8 af = *(const short8*)&Pw[lq * 72 + kt * 32 + quad * 8];
      for (int nt = 0; nt < 8; nt++) {
        short8 bf = *(const short8*)&Vlds[(nt * 16 + lq) * 72 + kt * 32 + quad * 8];
        oacc[nt] = __builtin_amdgcn_mfma_f32_16x16x32_bf16(af, bf, oacc[nt], 0, 0, 0);
      }
    }
  }
  // epilogue: O / l -> ao[s][h*128+d] bf16
  float invl[4];
  for (int r = 0; r < 4; r++) invl[r] = 1.0f / lrun[r];
  for (int nt = 0; nt < 8; nt++) {
    for (int r = 0; r < 4; r++) {
      float v = oacc[nt][r] * invl[r];
      ao[(size_t)(i0 + w * 16 + quad * 4 + r) * C + h * 128 + nt * 16 + lq] = f2bf(v);
    }
  }
}

extern "C" void kernel_launch(void* const* d_in, const int* in_sizes, int n_in,
                              void* d_out, int out_size, void* d_ws, size_t ws_size,
                              hipStream_t stream) {
  const float* x    = (const float*)d_in[0];
  const float* rope = (const float*)d_in[1];
  const float* Wq   = (const float*)d_in[2];
  const float* bq   = (const float*)d_in[3];
  const float* Wk   = (const float*)d_in[4];
  const float* bk   = (const float*)d_in[5];
  const float* Wv   = (const float*)d_in[6];
  const float* bv   = (const float*)d_in[7];
  const float* qn_w = (const float*)d_in[8];
  const float* kn_w = (const float*)d_in[9];
  const float* Wo   = (const float*)d_in[10];
  const float* bo   = (const float*)d_in[11];
  float* out = (float*)d_out;

  // workspace layout (needs 128 MiB)
  unsigned short* xb  = (unsigned short*)d_ws;          // S*C bf16
  unsigned short* wqb = xb  + (size_t)S * C;            // C*C
  unsigned short* wkb = wqb + (size_t)C * C;
  unsigned short* wvb = wkb + (size_t)C * C;
  unsigned short* wob = wvb + (size_t)C * C;
  unsigned short* qh  = wob + (size_t)C * C;            // [H][S][D]
  unsigned short* kh  = qh  + (size_t)S * C;
  unsigned short* vh  = kh  + (size_t)S * C;
  unsigned short* vt  = vh  + (size_t)S * C;            // [H][D][S]
  unsigned short* ao  = vt  + (size_t)S * C;            // [S][C]

  cvt_kernel<<<S * C / 1024, 256, 0, stream>>>(x, xb, S * C);
  cvt_kernel<<<C * C / 1024, 256, 0, stream>>>(Wq, wqb, C * C);
  cvt_kernel<<<C * C / 1024, 256, 0, stream>>>(Wk, wkb, C * C);
  cvt_kernel<<<C * C / 1024, 256, 0, stream>>>(Wv, wvb, C * C);
  cvt_kernel<<<C * C / 1024, 256, 0, stream>>>(Wo, wob, C * C);

  dim3 ggrid(C / 128, S / 128);
  gemm_bt<<<ggrid, 256, 0, stream>>>(xb, wqb, bq, (void*)qh, 1);
  gemm_bt<<<ggrid, 256, 0, stream>>>(xb, wkb, bk, (void*)kh, 1);
  gemm_bt<<<ggrid, 256, 0, stream>>>(xb, wvb, bv, (void*)vh, 1);

  rmsrope_kernel<<<(H * S) / 4, 256, 0, stream>>>(qh, qn_w, rope, SCALE);
  rmsrope_kernel<<<(H * S) / 4, 256, 0, stream>>>(kh, kn_w, rope, 1.0f);

  transpose_v<<<dim3(S / 64, D / 64, H), 256, 0, stream>>>(vh, vt);

  flash_kernel<<<dim3(S / 64, H), 256, 0, stream>>>(qh, kh, vt, ao);

  gemm_bt<<<ggrid, 256, 0, stream>>>(ao, wob, bo, (void*)out, 0);
}

// Round 2
// 609.369 us; speedup vs baseline: 1.5390x; 1.5390x over previous
//
#include <hip/hip_runtime.h>

#define S 4096
#define C 2048
#define H 16
#define D 128
#define EPS 1.1920929e-07f
#define SCALE 0.08838834764831845f  // 1/sqrt(128)

typedef __attribute__((ext_vector_type(8))) short short8;            // 8 bf16 (MFMA x32 A/B)
typedef __attribute__((ext_vector_type(4))) float f32x4;             // MFMA C/D
typedef __attribute__((ext_vector_type(4))) unsigned short ushort4v; // 4 bf16 (MFMA x16 A/B)

#if __has_builtin(__builtin_amdgcn_mfma_f32_16x16x16bf16_1k)
#define HAVE_MFMA16 1
#else
#define HAVE_MFMA16 0
#endif

__device__ __forceinline__ unsigned short f2bf(float f) {
  unsigned int u = __builtin_bit_cast(unsigned int, f);
  u += 0x7fff + ((u >> 16) & 1);  // RNE
  return (unsigned short)(u >> 16);
}
__device__ __forceinline__ float bf2f(unsigned short v) {
  unsigned int u = ((unsigned int)v) << 16;
  return __builtin_bit_cast(float, u);
}
__device__ __forceinline__ unsigned int pkbf(float a, float b) {
  return (unsigned int)f2bf(a) | ((unsigned int)f2bf(b) << 16);
}
// async global->LDS, 16B/lane; LDS dest = base + lane*16 (wave-uniform base)
__device__ __forceinline__ void gld16(const unsigned short* g, unsigned short* l) {
  __builtin_amdgcn_global_load_lds(
      (const __attribute__((address_space(1))) unsigned int*)g,
      (__attribute__((address_space(3))) unsigned int*)l, 16, 0, 0);
}

// ---------------- fp32 -> bf16 converts ----------------
__global__ void cvt_kernel(const float* __restrict__ src,
                           unsigned short* __restrict__ dst, int n) {
  int i = (blockIdx.x * 256 + threadIdx.x) * 4;
  if (i >= n) return;
  float4 v = *(const float4*)(src + i);
  ushort4 o;
  o.x = f2bf(v.x); o.y = f2bf(v.y); o.z = f2bf(v.z); o.w = f2bf(v.w);
  *(ushort4*)(dst + i) = o;
}
__global__ void cvtw_kernel(const float* __restrict__ w0, const float* __restrict__ w1,
                            const float* __restrict__ w2, const float* __restrict__ w3,
                            unsigned short* __restrict__ dst) {
  const float* srcs[4] = {w0, w1, w2, w3};
  const float* src = srcs[blockIdx.y];
  int i = (blockIdx.x * 256 + threadIdx.x) * 4;
  float4 v = *(const float4*)(src + i);
  ushort4 o;
  o.x = f2bf(v.x); o.y = f2bf(v.y); o.z = f2bf(v.z); o.w = f2bf(v.w);
  *(ushort4*)(dst + (size_t)blockIdx.y * C * C + i) = o;
}
__global__ void bias_concat(const float* __restrict__ bq, const float* __restrict__ bk,
                            const float* __restrict__ bv, float* __restrict__ dst) {
  int i = blockIdx.x * 256 + threadIdx.x;  // 0..6143
  const float* s = (i < C) ? bq : ((i < 2 * C) ? bk : bv);
  dst[i] = s[i & (C - 1)];
}

// ---------------- bf16 GEMM (m97 structure): out[m][n] = sum_k A[m][k]*B[n][k] + bias[n]
// M=S fixed, K=C fixed, N param. mode 0: fp32 [M][N]; mode 1: bf16 head layout [n>>7][m][n&127].
__global__ __launch_bounds__(256) void gemm_bt(const unsigned short* __restrict__ A,
                                               const unsigned short* __restrict__ B,
                                               const float* __restrict__ bias,
                                               void* __restrict__ out, int N, int mode) {
  __shared__ __align__(16) unsigned short Al[128 * 64];  // unpadded, XOR-swizzled groups
  __shared__ __align__(16) unsigned short Bl[128 * 64];
  const int t = threadIdx.x, w = t >> 6, lane = t & 63;
  const int lq = lane & 15, quad = lane >> 4;
  const int wm = w & 1, wn = w >> 1;
  const int m0 = blockIdx.y * 128, n0 = blockIdx.x * 128;
  f32x4 acc[4][4] = {};
  float biasv[4];
  for (int nt = 0; nt < 4; nt++) biasv[nt] = bias[n0 + wn * 64 + nt * 16 + lq];
  const int sr = lane >> 3, sg = lane & 7;  // 8 rows/call, 8 lanes/row (64B/row? no: 64sh=128B)
  for (int k0 = 0; k0 < C; k0 += 64) {
    __syncthreads();
    for (int p = 0; p < 4; p++) {
      int row = w * 32 + p * 8 + sr;
      int c = sg ^ (row & 7);  // swizzle on the global source; LDS stays lane-linear
      gld16(A + (size_t)(m0 + row) * C + k0 + c * 8, &Al[(w * 32 + p * 8) * 64]);
      gld16(B + (size_t)(n0 + row) * C + k0 + c * 8, &Bl[(w * 32 + p * 8) * 64]);
    }
    __syncthreads();
    for (int ks = 0; ks < 2; ks++) {
      short8 af[4], bf[4];
      for (int mt = 0; mt < 4; mt++) {
        int row = wm * 64 + mt * 16 + lq;
        af[mt] = *(const short8*)&Al[row * 64 + ((ks * 4 + quad) ^ (lq & 7)) * 8];
      }
      for (int nt = 0; nt < 4; nt++) {
        int row = wn * 64 + nt * 16 + lq;
        bf[nt] = *(const short8*)&Bl[row * 64 + ((ks * 4 + quad) ^ (lq & 7)) * 8];
      }
      for (int mt = 0; mt < 4; mt++)
        for (int nt = 0; nt < 4; nt++)
          acc[mt][nt] = __builtin_amdgcn_mfma_f32_16x16x32_bf16(af[mt], bf[nt], acc[mt][nt], 0, 0, 0);
    }
  }
  for (int mt = 0; mt < 4; mt++)
    for (int nt = 0; nt < 4; nt++) {
      int n = n0 + wn * 64 + nt * 16 + lq;
      for (int r = 0; r < 4; r++) {
        int m = m0 + wm * 64 + mt * 16 + quad * 4 + r;  // C/D: col=lane&15, row=quad*4+r
        float v = acc[mt][nt][r] + biasv[nt];
        if (mode == 0) ((float*)out)[(size_t)m * N + n] = v;
        else ((unsigned short*)out)[(size_t)(n >> 7) * S * D + (size_t)m * D + (n & 127)] = f2bf(v);
      }
    }
}

// ---------------- fused RMSNorm + rotary, in place on [H][S][D] bf16 ----------------
__global__ __launch_bounds__(256) void rmsrope_kernel(unsigned short* __restrict__ io,
                                                      const float* __restrict__ wgt,
                                                      const float* __restrict__ rope,
                                                      float scale) {
  int wid = (blockIdx.x * 256 + threadIdx.x) >> 6;  // wave id = h*S + s
  int lane = threadIdx.x & 63;
  int s = wid & (S - 1);
  unsigned short* row = io + (size_t)wid * D;
  unsigned int pr = *(unsigned int*)(row + lane * 2);
  float a = bf2f((unsigned short)(pr & 0xffff));
  float b = bf2f((unsigned short)(pr >> 16));
  float ss = a * a + b * b;
  for (int m = 1; m < 64; m <<= 1) ss += __shfl_xor(ss, m);
  float inv = rsqrtf(ss * (1.0f / 128.0f) + EPS);
  float2 wv = *(const float2*)(wgt + lane * 2);
  float an = a * inv * wv.x, bn = b * inv * wv.y;
  float4 r = *(const float4*)(rope + (size_t)s * 256 + lane * 4);
  float o0 = (r.x * an + r.y * bn) * scale;
  float o1 = (r.z * an + r.w * bn) * scale;
  *(unsigned int*)(row + lane * 2) = pkbf(o0, o1);
}

// ---------------- V transpose: [H][S][D] -> [H][D][S] ----------------
__global__ __launch_bounds__(256) void transpose_v(const unsigned short* __restrict__ vh,
                                                   unsigned short* __restrict__ vt) {
  __shared__ unsigned short tile[64][72];
  int h = blockIdx.z, s0 = blockIdx.x * 64, d0 = blockIdx.y * 64;
  int t = threadIdx.x;
  for (int p = 0; p < 2; p++) {
    int sl = p * 32 + (t >> 3);
    int d8 = (t & 7) * 8;
    *(uint4*)&tile[sl][d8] = *(const uint4*)(vh + ((size_t)h * S + s0 + sl) * D + d0 + d8);
  }
  __syncthreads();
  for (int p = 0; p < 2; p++) {
    int dl = p * 32 + (t >> 3);
    int s8 = (t & 7) * 8;
    unsigned short vals[8];
    for (int i = 0; i < 8; i++) vals[i] = tile[s8 + i][dl];
    *(uint4*)(vt + ((size_t)h * D + d0 + dl) * S + s0 + s8) = *(uint4*)vals;
  }
}

// ---------------- flash attention: computes S^T = K·Q^T so softmax rows sit on lane&15
// and P is born in A-layout for K=16 PV MFMAs (no cross-lane transpose).
__global__ __launch_bounds__(256, 4) void flash_kernel(const unsigned short* __restrict__ qh,
                                                       const unsigned short* __restrict__ kh,
                                                       const unsigned short* __restrict__ vt,
                                                       unsigned short* __restrict__ ao) {
  __shared__ __align__(16) unsigned short Klds[64 * 128];  // [j][d], swizzled
  __shared__ __align__(16) unsigned short Vlds[128 * 64];  // [d][j], swizzled
#if !HAVE_MFMA16
  __shared__ __align__(16) unsigned short Plds[4 * 16 * 72];
#endif
  const int h = blockIdx.y, i0 = blockIdx.x * 64;
  const int t = threadIdx.x, w = t >> 6, lane = t & 63;
  const int lq = lane & 15, quad = lane >> 4;

  // Q as MFMA B-operand: n=lq (q row), k=quad*8+j (d). scale pre-folded by rmsrope.
  const unsigned short* Qbase = qh + ((size_t)h * S + i0 + w * 16 + lq) * D;
  short8 qfrag[4];
  for (int kt = 0; kt < 4; kt++) qfrag[kt] = *(const short8*)(Qbase + kt * 32 + quad * 8);

  f32x4 oacc[8] = {};
  float mrun = -1e30f, lrun = 0.0f;  // per-lane state for q-row = lq (replicated over quads)
  const unsigned short* Kbase = kh + (size_t)h * S * D;
  const unsigned short* Vbase = vt + (size_t)h * D * S;

  const int kr = lane >> 4, kg = lane & 15;  // K stage: 4 rows/call, 16 lanes/row
  const int vr = lane >> 3, vg = lane & 7;   // V stage: 8 rows/call, 8 lanes/row

  for (int j0 = 0; j0 < S; j0 += 64) {
    __syncthreads();
    for (int p = 0; p < 4; p++) {
      int krow = w * 16 + p * 4 + kr;
      gld16(Kbase + (size_t)(j0 + krow) * D + (kg ^ (krow & 7)) * 8,
            &Klds[(w * 16 + p * 4) * 128]);
      int vrow = w * 32 + p * 8 + vr;
      gld16(Vbase + (size_t)vrow * S + j0 + (vg ^ (vrow & 7)) * 8,
            &Vlds[(w * 32 + p * 8) * 64]);
    }
    __syncthreads();

    // S^T = K·Q^T : sacc[nt][r] = S[q=lq][j = j0 + nt*16 + quad*4 + r]
    f32x4 sacc[4] = {};
    for (int kt = 0; kt < 4; kt++)
      for (int nt = 0; nt < 4; nt++) {
        int row = nt * 16 + lq;
        short8 af = *(const short8*)&Klds[row * 128 + ((kt * 4 + quad) ^ (lq & 7)) * 8];
        sacc[nt] = __builtin_amdgcn_mfma_f32_16x16x32_bf16(af, qfrag[kt], sacc[nt], 0, 0, 0);
      }

    // online softmax for row lq: in-lane reduce over 16, cross-quad via shfl 16/32
    float vmax = sacc[0][0];
    for (int nt = 0; nt < 4; nt++)
      for (int r = 0; r < 4; r++) vmax = fmaxf(vmax, sacc[nt][r]);
    vmax = fmaxf(vmax, __shfl_xor(vmax, 16));
    vmax = fmaxf(vmax, __shfl_xor(vmax, 32));
    float mnew = fmaxf(mrun, vmax);
    float alpha = __expf(mrun - mnew);
    float pv[4][4];
    float rsum = 0.0f;
    for (int nt = 0; nt < 4; nt++)
      for (int r = 0; r < 4; r++) {
        float e = __expf(sacc[nt][r] - mnew);
        pv[nt][r] = e;
        rsum += e;
      }
    rsum += __shfl_xor(rsum, 16);
    rsum += __shfl_xor(rsum, 32);
    lrun = lrun * alpha + rsum;
    mrun = mnew;
    // rescale O rows (row = quad*4+r) with alpha held at lane = that row
    for (int r = 0; r < 4; r++) {
      float ar = __shfl(alpha, quad * 4 + r);
      for (int dt = 0; dt < 8; dt++) oacc[dt][r] *= ar;
    }

#if HAVE_MFMA16
    // P already in A-layout for 16x16x16: A[m=lq][k=quad*4+j]
    for (int ntk = 0; ntk < 4; ntk++) {
      ushort4v af;
      af.x = f2bf(pv[ntk][0]); af.y = f2bf(pv[ntk][1]);
      af.z = f2bf(pv[ntk][2]); af.w = f2bf(pv[ntk][3]);
      int g = 2 * ntk + (quad >> 1);      // logical 16B group of j-col quad*4 within block ntk
      int go = (quad & 1) * 4;            // short offset within group
      for (int dt = 0; dt < 8; dt++) {
        int row = dt * 16 + lq;
        ushort4v bf = *(const ushort4v*)&Vlds[row * 64 + (g ^ (row & 7)) * 8 + go];
        oacc[dt] = __builtin_amdgcn_mfma_f32_16x16x16bf16_1k(af, bf, oacc[dt], 0, 0, 0);
      }
    }
#else
    // fallback: packed-dword LDS round trip (wave-local, no barrier)
    unsigned short* Pw = Plds + w * 16 * 72;
    for (int nt = 0; nt < 4; nt++) {
      *(unsigned int*)&Pw[lq * 72 + nt * 16 + quad * 4] = pkbf(pv[nt][0], pv[nt][1]);
      *(unsigned int*)&Pw[lq * 72 + nt * 16 + quad * 4 + 2] = pkbf(pv[nt][2], pv[nt][3]);
    }
    for (int kt = 0; kt < 2; kt++) {
      short8 af = *(const short8*)&Pw[lq * 72 + kt * 32 + quad * 8];
      for (int dt = 0; dt < 8; dt++) {
        int row = dt * 16 + lq;
        short8 bf = *(const short8*)&Vlds[row * 64 + ((kt * 4 + quad) ^ (lq & 7)) * 8];
        oacc[dt] = __builtin_amdgcn_mfma_f32_16x16x32_bf16(af, bf, oacc[dt], 0, 0, 0);
      }
    }
#endif
  }

  float il[4];
  for (int r = 0; r < 4; r++) il[r] = 1.0f / __shfl(lrun, quad * 4 + r);
  for (int dt = 0; dt < 8; dt++)
    for (int r = 0; r < 4; r++)
      ao[(size_t)(i0 + w * 16 + quad * 4 + r) * C + h * 128 + dt * 16 + lq] =
          f2bf(oacc[dt][r] * il[r]);
}

extern "C" void kernel_launch(void* const* d_in, const int* in_sizes, int n_in,
                              void* d_out, int out_size, void* d_ws, size_t ws_size,
                              hipStream_t stream) {
  const float* x    = (const float*)d_in[0];
  const float* rope = (const float*)d_in[1];
  const float* Wq   = (const float*)d_in[2];
  const float* bq   = (const float*)d_in[3];
  const float* Wk   = (const float*)d_in[4];
  const float* bk   = (const float*)d_in[5];
  const float* Wv   = (const float*)d_in[6];
  const float* bv   = (const float*)d_in[7];
  const float* qn_w = (const float*)d_in[8];
  const float* kn_w = (const float*)d_in[9];
  const float* Wo   = (const float*)d_in[10];
  const float* bo   = (const float*)d_in[11];
  float* out = (float*)d_out;

  unsigned short* xb  = (unsigned short*)d_ws;      // S*C
  unsigned short* wqb = xb + (size_t)S * C;         // 4*C*C (Wq,Wk,Wv,Wo contiguous)
  unsigned short* wob = wqb + (size_t)3 * C * C;
  unsigned short* qh  = wqb + (size_t)4 * C * C;    // [48][S][D]: q(16) k(16) v(16) heads
  unsigned short* kh  = qh + (size_t)S * C;
  unsigned short* vh  = kh + (size_t)S * C;
  unsigned short* vt  = vh + (size_t)S * C;         // [H][D][S]
  unsigned short* ao  = vt + (size_t)S * C;         // [S][C]
  float* bqkv = (float*)(ao + (size_t)S * C);       // 6144 floats

  cvt_kernel<<<S * C / 1024, 256, 0, stream>>>(x, xb, S * C);
  cvtw_kernel<<<dim3(C * C / 1024, 4), 256, 0, stream>>>(Wq, Wk, Wv, Wo, wqb);
  bias_concat<<<3 * C / 256, 256, 0, stream>>>(bq, bk, bv, bqkv);

  // fused QKV projection: N = 3*C = 6144, head-layout epilogue lands q/k/v contiguously
  gemm_bt<<<dim3(3 * C / 128, S / 128), 256, 0, stream>>>(xb, wqb, bqkv, (void*)qh, 3 * C, 1);

  rmsrope_kernel<<<(H * S) / 4, 256, 0, stream>>>(qh, qn_w, rope, SCALE);
  rmsrope_kernel<<<(H * S) / 4, 256, 0, stream>>>(kh, kn_w, rope, 1.0f);

  transpose_v<<<dim3(S / 64, D / 64, H), 256, 0, stream>>>(vh, vt);

  flash_kernel<<<dim3(S / 64, H), 256, 0, stream>>>(qh, kh, vt, ao);

  gemm_bt<<<dim3(C / 128, S / 128), 256, 0, stream>>>(ao, wob, bo, (void*)out, C, 0);
}